// Round 4
// baseline (284.073 us; speedup 1.0000x reference)
//
#include <hip/hip_runtime.h>

#define IN_H 512
#define IN_W 512
#define OUT_H 224
#define OUT_W 224
#define OY 8            // output rows per block
#define BLOCK 256
#define NTILE (OUT_H / OY)          // 28 row-tiles per image
#define NIMG  (64 * 3)              // 192
#define NWG   (NIMG * NTILE)        // 5376, divisible by 8

// Antialiased bilinear 512->224 (scale 7/16), separable triangle kernel,
// per-dim normalized weights, max 5 taps/dim.
// Vertical-first fused: vertical reduction straight from global (coalesced
// float4, taps at row stride) into LDS, then horizontal gather from LDS.
// R3: OY=8, y-weight LUT in LDS, XCD-chunked block swizzle for halo L2 reuse.

__global__ __launch_bounds__(BLOCK) void resize_aa_vfirst(
    const float* __restrict__ in, float* __restrict__ out) {

    __shared__ float s_v[OY][IN_W];     // 16384 B (vertically resized rows)
    __shared__ float s_wx[OUT_W][5];    // 4480 B  (pre-normalized x weights)
    __shared__ int   s_ix0[OUT_W];      // 896 B
    __shared__ float s_wy[OY][5];       // 160 B   (pre-normalized y weights)
    __shared__ int   s_iy0[OY];         // 32 B

    // ---- XCD-chunked bijective swizzle (NWG % 8 == 0) ----
    int bid  = blockIdx.x;
    int wg   = (bid & 7) * (NWG / 8) + (bid >> 3);
    int img  = wg / NTILE;
    int tile = wg - img * NTILE;
    const int oy0 = tile * OY;
    const int tid = threadIdx.x;

    const float inv_scale = 16.f / 7.f;  // in/out = 2.285714
    const float scl       = 7.f / 16.f;  // out/in

    // ---- weight LUTs (once per block) ----
    if (tid < OUT_W) {
        float cx  = (tid + 0.5f) * inv_scale - 0.5f;
        int   ix0 = (int)ceilf(cx - inv_scale);
        float w[5];
        float s = 0.f;
#pragma unroll
        for (int j = 0; j < 5; ++j) {
            int i = ix0 + j;
            float ww = 1.f - fabsf(cx - (float)i) * scl;
            ww = fmaxf(ww, 0.f);
            if (i < 0 || i >= IN_W) ww = 0.f;
            w[j] = ww;
            s += ww;
        }
        float invs = 1.f / s;
#pragma unroll
        for (int j = 0; j < 5; ++j) s_wx[tid][j] = w[j] * invs;
        s_ix0[tid] = ix0;
    } else if (tid >= 240 && tid < 240 + OY) {
        int   t   = tid - 240;
        float cy  = (oy0 + t + 0.5f) * inv_scale - 0.5f;
        int   iy0 = (int)ceilf(cy - inv_scale);
        float w[5];
        float s = 0.f;
#pragma unroll
        for (int j = 0; j < 5; ++j) {
            int i = iy0 + j;
            float ww = 1.f - fabsf(cy - (float)i) * scl;
            ww = fmaxf(ww, 0.f);
            if (i < 0 || i >= IN_H) ww = 0.f;
            w[j] = ww;
            s += ww;
        }
        float invs = 1.f / s;
#pragma unroll
        for (int j = 0; j < 5; ++j) s_wy[t][j] = w[j] * invs;
        s_iy0[t] = iy0;
    }

    __syncthreads();

    // ---- vertical pass: global (coalesced float4) -> s_v ----
    // OY*128 = 1024 float4 quads, 4 per thread; t is wave-uniform.
    const float* src = in + (size_t)img * (IN_H * IN_W);
#pragma unroll
    for (int k = 0; k < OY * (IN_W / 4) / BLOCK; ++k) {
        int q  = tid + k * BLOCK;
        int t  = q >> 7;                 // quad row (0..OY-1)
        int x0 = (q & 127) << 2;         // column of this float4
        int iy0 = s_iy0[t];
        float4 acc = make_float4(0.f, 0.f, 0.f, 0.f);
#pragma unroll
        for (int j = 0; j < 5; ++j) {
            float ww = s_wy[t][j];
            int r = min(max(iy0 + j, 0), IN_H - 1);
            float4 v = *(const float4*)(src + (size_t)r * IN_W + x0);
            acc.x = fmaf(ww, v.x, acc.x);
            acc.y = fmaf(ww, v.y, acc.y);
            acc.z = fmaf(ww, v.z, acc.z);
            acc.w = fmaf(ww, v.w, acc.w);
        }
        *(float4*)(&s_v[t][x0]) = acc;
    }

    __syncthreads();

    // ---- horizontal pass: s_v -> out (coalesced store) ----
    for (int idx = tid; idx < OY * OUT_W; idx += BLOCK) {
        int t  = idx / OUT_W;
        int ox = idx - t * OUT_W;
        int ix0 = s_ix0[ox];
        float acc = 0.f;
#pragma unroll
        for (int j = 0; j < 5; ++j) {
            int c = min(max(ix0 + j, 0), IN_W - 1);  // OOB taps have w=0
            acc = fmaf(s_wx[ox][j], s_v[t][c], acc);
        }
        out[((size_t)img * OUT_H + (oy0 + t)) * OUT_W + ox] = acc;
    }
}

extern "C" void kernel_launch(void* const* d_in, const int* in_sizes, int n_in,
                              void* d_out, int out_size, void* d_ws, size_t ws_size,
                              hipStream_t stream) {
    const float* in = (const float*)d_in[0];
    float* out = (float*)d_out;
    dim3 block(BLOCK);
    dim3 grid(NWG);   // 5376
    hipLaunchKernelGGL(resize_aa_vfirst, grid, block, 0, stream, in, out);
}

// Round 5
// 279.994 us; speedup vs baseline: 1.0146x; 1.0146x over previous
//
#include <hip/hip_runtime.h>

#define IN_H 512
#define IN_W 512
#define OUT_H 224
#define OUT_W 224
#define BLOCK 256
#define OYB 4                         // 4 waves/block, 1 output row each
#define NTILE (OUT_H / OYB)           // 56 row-groups per image
#define NIMG  (64 * 3)                // 192
#define NWG   (NIMG * NTILE)          // 10752, divisible by 8

// Antialiased bilinear 512->224 (scale 7/16), separable triangle kernel,
// per-dim normalized weights, max 5 taps/dim.
// R4: wave-autonomous. Each wave: vertical 5-tap from global (coalesced
// float4) -> wave-private LDS strip (no barrier, intra-wave lgkmcnt only)
// -> horizontal gather -> store. Single early barrier for the shared x-LUT.

__global__ __launch_bounds__(BLOCK) void resize_aa_wave(
    const float* __restrict__ in, float* __restrict__ out) {

    __shared__ float s_v[OYB][IN_W];    // 8192 B, one strip per wave
    __shared__ float s_wx[OUT_W][5];    // 4480 B pre-normalized x weights
    __shared__ int   s_ix0[OUT_W];      // 896 B

    const int tid  = threadIdx.x;
    const int wave = tid >> 6;
    const int lane = tid & 63;

    // ---- XCD-chunked bijective swizzle (NWG % 8 == 0) ----
    int bid  = blockIdx.x;
    int wg   = (bid & 7) * (NWG / 8) + (bid >> 3);
    int img  = wg / NTILE;
    int tile = wg - img * NTILE;
    const int oy = tile * OYB + wave;   // this wave's output row

    const float inv_scale = 16.f / 7.f;  // 2.285714
    const float scl       = 7.f / 16.f;  // 0.4375

    // ---- shared x-weight LUT, one early barrier ----
    if (tid < OUT_W) {
        float cx  = (tid + 0.5f) * inv_scale - 0.5f;
        int   ix0 = (int)ceilf(cx - inv_scale);
        float w[5];
        float s = 0.f;
#pragma unroll
        for (int j = 0; j < 5; ++j) {
            int i = ix0 + j;
            float ww = 1.f - fabsf(cx - (float)i) * scl;
            ww = fmaxf(ww, 0.f);
            if (i < 0 || i >= IN_W) ww = 0.f;
            w[j] = ww;
            s += ww;
        }
        float invs = 1.f / s;
#pragma unroll
        for (int j = 0; j < 5; ++j) s_wx[tid][j] = w[j] * invs;
        s_ix0[tid] = ix0;
    }
    __syncthreads();   // the only block barrier

    // ---- per-wave y weights (redundant across lanes, branchless) ----
    float cy  = (oy + 0.5f) * inv_scale - 0.5f;
    int   iy0 = (int)ceilf(cy - inv_scale);
    float wy[5];
    int   ry[5];
    float sy = 0.f;
#pragma unroll
    for (int j = 0; j < 5; ++j) {
        int i = iy0 + j;
        float ww = 1.f - fabsf(cy - (float)i) * scl;
        ww = fmaxf(ww, 0.f);
        if (i < 0 || i >= IN_H) ww = 0.f;
        wy[j] = ww;
        sy += ww;
        ry[j] = min(max(i, 0), IN_H - 1);
    }
    float invsy = 1.f / sy;
#pragma unroll
    for (int j = 0; j < 5; ++j) wy[j] *= invsy;

    // ---- vertical: 5 tap rows, 2 float4 per lane per row ----
    const float* src = in + (size_t)img * (IN_H * IN_W);
    float4 a0 = make_float4(0.f, 0.f, 0.f, 0.f);
    float4 a1 = make_float4(0.f, 0.f, 0.f, 0.f);
#pragma unroll
    for (int j = 0; j < 5; ++j) {
        const float* rp = src + (size_t)ry[j] * IN_W;
        float4 v0 = *(const float4*)(rp + 4 * lane);            // cols 0..255
        float4 v1 = *(const float4*)(rp + 256 + 4 * lane);      // cols 256..511
        float  w  = wy[j];
        a0.x = fmaf(w, v0.x, a0.x); a0.y = fmaf(w, v0.y, a0.y);
        a0.z = fmaf(w, v0.z, a0.z); a0.w = fmaf(w, v0.w, a0.w);
        a1.x = fmaf(w, v1.x, a1.x); a1.y = fmaf(w, v1.y, a1.y);
        a1.z = fmaf(w, v1.z, a1.z); a1.w = fmaf(w, v1.w, a1.w);
    }
    *(float4*)(&s_v[wave][4 * lane])       = a0;
    *(float4*)(&s_v[wave][256 + 4 * lane]) = a1;
    // intra-wave LDS dependency: compiler inserts s_waitcnt lgkmcnt — no barrier

    // ---- horizontal: 224 outputs per wave ----
    float* orow = out + ((size_t)img * OUT_H + oy) * OUT_W;
#pragma unroll
    for (int i = 0; i < 4; ++i) {
        int ox = i * 64 + lane;
        if (i < 3 || ox < OUT_W) {
            int ix0 = s_ix0[ox];
            float acc = 0.f;
#pragma unroll
            for (int j = 0; j < 5; ++j) {
                int c = min(max(ix0 + j, 0), IN_W - 1);  // OOB taps have w=0
                acc = fmaf(s_wx[ox][j], s_v[wave][c], acc);
            }
            orow[ox] = acc;
        }
    }
}

extern "C" void kernel_launch(void* const* d_in, const int* in_sizes, int n_in,
                              void* d_out, int out_size, void* d_ws, size_t ws_size,
                              hipStream_t stream) {
    const float* in = (const float*)d_in[0];
    float* out = (float*)d_out;
    dim3 block(BLOCK);
    dim3 grid(NWG);   // 10752
    hipLaunchKernelGGL(resize_aa_wave, grid, block, 0, stream, in, out);
}